// Round 2
// baseline (250.370 us; speedup 1.0000x reference)
//
#include <hip/hip_runtime.h>
#include <hip/hip_bf16.h>

typedef unsigned short u16;
typedef __attribute__((ext_vector_type(8))) short bf16x8;
typedef __attribute__((ext_vector_type(4))) short short4v;
typedef __attribute__((ext_vector_type(4))) float floatx4;

__device__ __forceinline__ float bf2f(u16 u) {
    unsigned v = ((unsigned)u) << 16;
    return __builtin_bit_cast(float, v);
}
__device__ __forceinline__ u16 f2bf(float f) {
    unsigned u = __builtin_bit_cast(unsigned, f);
    u += 0x7fffu + ((u >> 16) & 1u);   // RNE
    return (u16)(u >> 16);
}

#define GLDS16(g, l)                                                             \
    __builtin_amdgcn_global_load_lds(                                            \
        (const __attribute__((address_space(1))) void*)(g),                      \
        (__attribute__((address_space(3))) void*)(l), 16, 0, 0)

// ---------------------------------------------------------------------------
// fp32 -> bf16 elementwise (x), vectorized 4/thread
// ---------------------------------------------------------------------------
__global__ __launch_bounds__(256) void cvt_bf16(const float* __restrict__ in, u16* __restrict__ out) {
    const int i = blockIdx.x * 256 + threadIdx.x;
    const floatx4 v = ((const floatx4*)in)[i];
    short4v o;
#pragma unroll
    for (int j = 0; j < 4; ++j) o[j] = (short)f2bf(v[j]);
    ((short4v*)out)[i] = o;
}

// ---------------------------------------------------------------------------
// fp32 weight transpose + bf16 convert: in [R][C] fp32 row-major -> out [C][R] bf16
// ---------------------------------------------------------------------------
__global__ void wtrans(const float* __restrict__ in, u16* __restrict__ out, int R, int C) {
    __shared__ u16 t[32][33];
    const int c0 = blockIdx.x * 32, r0 = blockIdx.y * 32;
    const int x = threadIdx.x, y = threadIdx.y;
#pragma unroll
    for (int i = 0; i < 32; i += 8) t[y + i][x] = f2bf(in[(size_t)(r0 + y + i) * C + c0 + x]);
    __syncthreads();
#pragma unroll
    for (int i = 0; i < 32; i += 8) out[(size_t)(c0 + y + i) * R + r0 + x] = t[x][y + i];
}

// ---------------------------------------------------------------------------
// V transpose: h's V block [B, S, H, dh] (cols 2048..3071 of h, bf16) -> vt [B*H][dh][S]
// ---------------------------------------------------------------------------
__global__ void vtrans(const u16* __restrict__ h, u16* __restrict__ vt) {
    __shared__ u16 t[32][33];
    const int bh = blockIdx.z;                // b*16 + hd
    const int b = bh >> 4, hd = bh & 15;
    const int s0 = blockIdx.x * 32, d0 = blockIdx.y * 32;
    const int x = threadIdx.x, y = threadIdx.y;
    const u16* in = h + (size_t)(b * 2048) * 3072 + 2048 + hd * 64;
#pragma unroll
    for (int i = 0; i < 32; i += 8) t[y + i][x] = in[(size_t)(s0 + y + i) * 3072 + d0 + x];
    __syncthreads();
    u16* o = vt + (size_t)bh * 64 * 2048;
#pragma unroll
    for (int i = 0; i < 32; i += 8) o[(size_t)(d0 + y + i) * 2048 + s0 + x] = t[x][y + i];
}

// ---------------------------------------------------------------------------
// m97-style GEMM: C[M,N] = A[M,K] @ Bt[N,K]^T (+bias), bf16 in, fp32 acc
// OUT = u16 (bf16 store) or float (fp32 store). block 256, tile 128x128, BK=32
// ---------------------------------------------------------------------------
template <bool BIAS, typename OUT>
__global__ __launch_bounds__(256) void gemm_bt(const u16* __restrict__ A, const u16* __restrict__ Bt,
                                               OUT* __restrict__ C, const float* __restrict__ bias,
                                               int M, int N, int K) {
    __shared__ u16 sA[128 * 32];
    __shared__ u16 sB[128 * 32];
    const int tid = threadIdx.x;
    const int lane = tid & 63, wave = tid >> 6;
    const int l15 = lane & 15, quad = lane >> 4;
    const int row0 = blockIdx.y * 128, col0 = blockIdx.x * 128;
    const int wm = (wave & 1) * 64, wn = (wave >> 1) * 64;
    const int c_ = (tid & 3) << 3;  // 0,8,16,24
    floatx4 acc[4][4] = {};
    for (int k0 = 0; k0 < K; k0 += 32) {
#pragma unroll
        for (int it = 0; it < 2; ++it) {
            const int idx = it * 256 + tid;
            const int r = idx >> 2;
            GLDS16(A + (size_t)(row0 + r) * K + k0 + c_, sA + idx * 8);
            GLDS16(Bt + (size_t)(col0 + r) * K + k0 + c_, sB + idx * 8);
        }
        __syncthreads();
        bf16x8 af[4], bfr[4];
#pragma unroll
        for (int i = 0; i < 4; ++i) af[i] = *(const bf16x8*)(sA + (wm + i * 16 + l15) * 32 + quad * 8);
#pragma unroll
        for (int j = 0; j < 4; ++j) bfr[j] = *(const bf16x8*)(sB + (wn + j * 16 + l15) * 32 + quad * 8);
#pragma unroll
        for (int i = 0; i < 4; ++i)
#pragma unroll
            for (int j = 0; j < 4; ++j)
                acc[i][j] = __builtin_amdgcn_mfma_f32_16x16x32_bf16(af[i], bfr[j], acc[i][j], 0, 0, 0);
        __syncthreads();
    }
#pragma unroll
    for (int i = 0; i < 4; ++i) {
#pragma unroll
        for (int j = 0; j < 4; ++j) {
            const int col = col0 + wn + j * 16 + l15;
            const int row = row0 + wm + i * 16 + quad * 4;
            const float b = BIAS ? bias[col] : 0.f;
#pragma unroll
            for (int r = 0; r < 4; ++r) {
                const float v = acc[i][j][r] + b;
                if constexpr (sizeof(OUT) == 2)
                    C[(size_t)(row + r) * N + col] = (OUT)f2bf(v);
                else
                    C[(size_t)(row + r) * N + col] = (OUT)v;
            }
        }
    }
}

// ---------------------------------------------------------------------------
// Causal ReLU attention (no softmax): per block one (b, hd, 128-query tile).
// S^T = K·Q^T so the C-layout writeback of P to LDS [query][key] is b64-
// contiguous; P then feeds PV as an A-fragment directly. 64-key chunks.
// ---------------------------------------------------------------------------
__global__ __launch_bounds__(256) void relu_attn(const u16* __restrict__ h, const u16* __restrict__ vt,
                                                 float* __restrict__ o) {
    __shared__ u16 sK[64 * 72];    // [key][dh], padded stride 72
    __shared__ u16 sV[64 * 72];    // [dh][key], padded stride 72
    __shared__ u16 sP[128 * 72];   // [query][key-chunk], padded stride 72
    const int bid = blockIdx.x;
    const int qt = 15 - (bid >> 5);     // heaviest tiles dispatched first
    const int bh = bid & 31;
    const int b = bh >> 4, hd = bh & 15;
    const int tid = threadIdx.x, lane = tid & 63, wave = tid >> 6;
    const int l15 = lane & 15, quad = lane >> 4;
    const int q0 = qt * 128;

    // Q B-fragments live in registers for the whole kernel (wave owns 32 queries)
    const u16* qbase = h + (size_t)(b * 2048 + q0 + wave * 32) * 3072 + hd * 64;
    bf16x8 qf[2][2];
#pragma unroll
    for (int nt = 0; nt < 2; ++nt)
#pragma unroll
        for (int ks = 0; ks < 2; ++ks)
            qf[nt][ks] = *(const bf16x8*)(qbase + (size_t)(nt * 16 + l15) * 3072 + ks * 32 + quad * 8);

    floatx4 acc[2][4] = {};
    const u16* kbase = h + (size_t)(b * 2048) * 3072 + 1024 + hd * 64;
    const u16* vbase = vt + (size_t)bh * 64 * 2048;
    const int sr = tid >> 3;           // staging row 0..31 (+it*32)
    const int sc = (tid & 7) << 3;     // staging col 0..56
    const int nch = 2 * qt + 2;

    for (int kc = 0; kc < nch; ++kc) {
        const int c0 = kc * 64;
        // stage K [64 keys][64 dh] and V^T [64 dh][64 keys] into padded LDS
#pragma unroll
        for (int it = 0; it < 2; ++it) {
            const int r = it * 32 + sr;
            bf16x8 kv = *(const bf16x8*)(kbase + (size_t)(c0 + r) * 3072 + sc);
            bf16x8 vv = *(const bf16x8*)(vbase + (size_t)r * 2048 + c0 + sc);
            *(bf16x8*)(sK + r * 72 + sc) = kv;
            *(bf16x8*)(sV + r * 72 + sc) = vv;
        }
        __syncthreads();
        const bool dm = (kc >= 2 * qt);   // only diagonal chunks need the mask
        // S^T = K·Q^T ; relu, mask, *0.125 ; pack -> sP [query][key]
#pragma unroll
        for (int mt = 0; mt < 4; ++mt) {
            bf16x8 kf0 = *(const bf16x8*)(sK + (mt * 16 + l15) * 72 + quad * 8);
            bf16x8 kf1 = *(const bf16x8*)(sK + (mt * 16 + l15) * 72 + 32 + quad * 8);
#pragma unroll
            for (int nt = 0; nt < 2; ++nt) {
                floatx4 z = {0.f, 0.f, 0.f, 0.f};
                floatx4 s = __builtin_amdgcn_mfma_f32_16x16x32_bf16(kf0, qf[nt][0], z, 0, 0, 0);
                s = __builtin_amdgcn_mfma_f32_16x16x32_bf16(kf1, qf[nt][1], s, 0, 0, 0);
                const int qg = q0 + wave * 32 + nt * 16 + l15;  // query (C col)
                const int kg = c0 + mt * 16 + quad * 4;         // key   (C row)
                short4v pk;
#pragma unroll
                for (int r = 0; r < 4; ++r) {
                    float v = fmaxf(s[r], 0.f) * 0.125f;        // dh^-0.5 folded post-relu
                    if (dm && (kg + r > qg)) v = 0.f;           // causal: keep key<=query
                    pk[r] = (short)f2bf(v);
                }
                *(short4v*)(sP + (size_t)(wave * 32 + nt * 16 + l15) * 72 + mt * 16 + quad * 4) = pk;
            }
        }
        // PV: O[query][dh] += P·V  (wave reads only its own P rows -> no barrier;
        // DS ops from one wave are processed in order)
#pragma unroll
        for (int kb = 0; kb < 2; ++kb) {
            bf16x8 pf0 = *(const bf16x8*)(sP + (wave * 32 + l15) * 72 + kb * 32 + quad * 8);
            bf16x8 pf1 = *(const bf16x8*)(sP + (wave * 32 + 16 + l15) * 72 + kb * 32 + quad * 8);
#pragma unroll
            for (int nt = 0; nt < 4; ++nt) {
                bf16x8 vf = *(const bf16x8*)(sV + (nt * 16 + l15) * 72 + kb * 32 + quad * 8);
                acc[0][nt] = __builtin_amdgcn_mfma_f32_16x16x32_bf16(pf0, vf, acc[0][nt], 0, 0, 0);
                acc[1][nt] = __builtin_amdgcn_mfma_f32_16x16x32_bf16(pf1, vf, acc[1][nt], 0, 0, 0);
            }
        }
        __syncthreads();
    }
    // epilogue: write combined-head fp32 o [B,S,D]
#pragma unroll
    for (int mq = 0; mq < 2; ++mq) {
#pragma unroll
        for (int nt = 0; nt < 4; ++nt) {
            const int col = hd * 64 + nt * 16 + l15;
            const int row = q0 + wave * 32 + mq * 16 + quad * 4;
#pragma unroll
            for (int r = 0; r < 4; ++r)
                o[(size_t)(b * 2048 + row + r) * 1024 + col] = acc[mq][nt][r];
        }
    }
}

// ---------------------------------------------------------------------------
// Gated RMSNorm: one block per row of o [4096][1024] fp32 -> bf16
// ---------------------------------------------------------------------------
__global__ __launch_bounds__(256) void rms_gate(const float* __restrict__ o, const float* __restrict__ scale,
                                                const float* __restrict__ gate, u16* __restrict__ out) {
    const int row = blockIdx.x;
    const int tid = threadIdx.x;
    const floatx4* op = (const floatx4*)(o + (size_t)row * 1024);
    floatx4 v = op[tid];
    float ss = v[0] * v[0] + v[1] * v[1] + v[2] * v[2] + v[3] * v[3];
#pragma unroll
    for (int m = 32; m >= 1; m >>= 1) ss += __shfl_xor(ss, m, 64);
    __shared__ float red[4];
    if ((tid & 63) == 0) red[tid >> 6] = ss;
    __syncthreads();
    const float ms = (red[0] + red[1] + red[2] + red[3]) * (1.0f / 1024.0f);
    const float inv = rsqrtf(ms + 1e-7f);
    const int c = tid * 4;
#pragma unroll
    for (int j = 0; j < 4; ++j) {
        const float s = scale[c + j];
        const float g = gate[c + j];
        const float x = v[j];
        const float sig = 1.0f / (1.0f + __expf(-g * x));
        out[(size_t)row * 1024 + c + j] = f2bf(s * x * inv * sig);
    }
}

// ---------------------------------------------------------------------------
extern "C" void kernel_launch(void* const* d_in, const int* in_sizes, int n_in,
                              void* d_out, int out_size, void* d_ws, size_t ws_size,
                              hipStream_t stream) {
    const float* x     = (const float*)d_in[0];   // [2,2048,1024] fp32
    // d_in[1] = mem_mask: structurally causal, applied analytically
    const float* Wqkv  = (const float*)d_in[2];   // [1024,3072] fp32
    const float* Wout  = (const float*)d_in[3];   // [1024,1024] fp32
    const float* bout  = (const float*)d_in[4];   // [1024] fp32
    const float* scale = (const float*)d_in[5];   // [1024] fp32
    const float* gate  = (const float*)d_in[6];   // [1024] fp32
    float* out = (float*)d_out;                   // [2,2048,1024] fp32

    char* p = (char*)d_ws;
    u16* xb    = (u16*)p; p += (size_t)4096 * 1024 * 2;    // x in bf16
    u16* h     = (u16*)p; p += (size_t)4096 * 3072 * 2;    // qkv projection (bf16)
    u16* vt    = (u16*)p; p += (size_t)32 * 64 * 2048 * 2; // V^T [bh][dh][s]
    u16* WqkvT = (u16*)p; p += (size_t)3072 * 1024 * 2;
    u16* WoutT = (u16*)p; p += (size_t)1024 * 1024 * 2;
    float* oat = (float*)p; p += (size_t)4096 * 1024 * 4;  // attention out fp32
    u16* onorm = (u16*)p; p += (size_t)4096 * 1024 * 2;

    cvt_bf16<<<4096, 256, 0, stream>>>(x, xb);
    wtrans<<<dim3(96, 32), dim3(32, 8), 0, stream>>>(Wqkv, WqkvT, 1024, 3072);
    wtrans<<<dim3(32, 32), dim3(32, 8), 0, stream>>>(Wout, WoutT, 1024, 1024);
    gemm_bt<false, u16><<<dim3(24, 32), 256, 0, stream>>>(xb, WqkvT, h, nullptr, 4096, 3072, 1024);
    vtrans<<<dim3(64, 2, 32), dim3(32, 8), 0, stream>>>(h, vt);
    relu_attn<<<512, 256, 0, stream>>>(h, vt, oat);
    rms_gate<<<4096, 256, 0, stream>>>(oat, scale, gate, onorm);
    gemm_bt<true, float><<<dim3(8, 32), 256, 0, stream>>>(onorm, WoutT, out, bout, 4096, 1024, 1024);
}

// Round 3
// 225.420 us; speedup vs baseline: 1.1107x; 1.1107x over previous
//
#include <hip/hip_runtime.h>
#include <hip/hip_bf16.h>

typedef unsigned short u16;
typedef __attribute__((ext_vector_type(8))) short bf16x8;
typedef __attribute__((ext_vector_type(4))) short short4v;
typedef __attribute__((ext_vector_type(4))) float floatx4;
typedef __attribute__((ext_vector_type(2))) unsigned uint2v;

__device__ __forceinline__ float bf2f(u16 u) {
    unsigned v = ((unsigned)u) << 16;
    return __builtin_bit_cast(float, v);
}
__device__ __forceinline__ u16 f2bf(float f) {
    unsigned u = __builtin_bit_cast(unsigned, f);
    u += 0x7fffu + ((u >> 16) & 1u);   // RNE
    return (u16)(u >> 16);
}

#define GLDS16(g, l)                                                             \
    __builtin_amdgcn_global_load_lds(                                            \
        (const __attribute__((address_space(1))) void*)(g),                      \
        (__attribute__((address_space(3))) void*)(l), 16, 0, 0)

// ---------------------------------------------------------------------------
// fp32 -> bf16 elementwise (x), vectorized 4/thread
// ---------------------------------------------------------------------------
__global__ __launch_bounds__(256) void cvt_bf16(const float* __restrict__ in, u16* __restrict__ out) {
    const int i = blockIdx.x * 256 + threadIdx.x;
    const floatx4 v = ((const floatx4*)in)[i];
    short4v o;
#pragma unroll
    for (int j = 0; j < 4; ++j) o[j] = (short)f2bf(v[j]);
    ((short4v*)out)[i] = o;
}

// ---------------------------------------------------------------------------
// fp32 weight transpose + bf16 convert: in [R][C] fp32 row-major -> out [C][R] bf16
// ---------------------------------------------------------------------------
__global__ void wtrans(const float* __restrict__ in, u16* __restrict__ out, int R, int C) {
    __shared__ u16 t[32][33];
    const int c0 = blockIdx.x * 32, r0 = blockIdx.y * 32;
    const int x = threadIdx.x, y = threadIdx.y;
#pragma unroll
    for (int i = 0; i < 32; i += 8) t[y + i][x] = f2bf(in[(size_t)(r0 + y + i) * C + c0 + x]);
    __syncthreads();
#pragma unroll
    for (int i = 0; i < 32; i += 8) out[(size_t)(c0 + y + i) * R + r0 + x] = t[x][y + i];
}

// ---------------------------------------------------------------------------
// V transpose + fold dh^-0.5 = 0.125 (exact pow2 scale): h's V block -> vt [B*H][dh][S]
// relu((q*c)·k)·v == relu(q·k)·(v*c) for c>0, so scale V once here.
// ---------------------------------------------------------------------------
__global__ void vtrans(const u16* __restrict__ h, u16* __restrict__ vt) {
    __shared__ u16 t[32][33];
    const int bh = blockIdx.z;                // b*16 + hd
    const int b = bh >> 4, hd = bh & 15;
    const int s0 = blockIdx.x * 32, d0 = blockIdx.y * 32;
    const int x = threadIdx.x, y = threadIdx.y;
    const u16* in = h + (size_t)(b * 2048) * 3072 + 2048 + hd * 64;
#pragma unroll
    for (int i = 0; i < 32; i += 8) t[y + i][x] = in[(size_t)(s0 + y + i) * 3072 + d0 + x];
    __syncthreads();
    u16* o = vt + (size_t)bh * 64 * 2048;
#pragma unroll
    for (int i = 0; i < 32; i += 8) {
        const float f = bf2f(t[x][y + i]) * 0.125f;  // exact: exponent shift only
        o[(size_t)(d0 + y + i) * 2048 + s0 + x] = (u16)(__builtin_bit_cast(unsigned, f) >> 16);
    }
}

// ---------------------------------------------------------------------------
// m97-style GEMM: C[M,N] = A[M,K] @ Bt[N,K]^T (+bias), bf16 in, fp32 acc
// Tile TM x 128, BK=32, block 256. OUT = u16 (bf16) or float.
// ---------------------------------------------------------------------------
template <int TM, bool BIAS, typename OUT>
__global__ __launch_bounds__(256) void gemm_bt(const u16* __restrict__ A, const u16* __restrict__ Bt,
                                               OUT* __restrict__ C, const float* __restrict__ bias,
                                               int M, int N, int K) {
    constexpr int MI = TM / 32;          // 16-row tiles per wave-row
    __shared__ u16 sA[TM * 32];
    __shared__ u16 sB[128 * 32];
    const int tid = threadIdx.x;
    const int lane = tid & 63, wave = tid >> 6;
    const int l15 = lane & 15, quad = lane >> 4;
    const int row0 = blockIdx.y * TM, col0 = blockIdx.x * 128;
    const int wm = (wave & 1) * (TM / 2), wn = (wave >> 1) * 64;
    const int c_ = (tid & 3) << 3;  // 0,8,16,24
    floatx4 acc[MI][4] = {};
    for (int k0 = 0; k0 < K; k0 += 32) {
#pragma unroll
        for (int it = 0; it < 2; ++it) {
            const int idx = it * 256 + tid;
            const int r = idx >> 2;
            GLDS16(Bt + (size_t)(col0 + r) * K + k0 + c_, sB + idx * 8);
        }
#pragma unroll
        for (int it = 0; it < TM / 64; ++it) {
            const int idx = it * 256 + tid;
            const int r = idx >> 2;
            GLDS16(A + (size_t)(row0 + r) * K + k0 + c_, sA + idx * 8);
        }
        __syncthreads();
        bf16x8 af[MI], bfr[4];
#pragma unroll
        for (int i = 0; i < MI; ++i) af[i] = *(const bf16x8*)(sA + (wm + i * 16 + l15) * 32 + quad * 8);
#pragma unroll
        for (int j = 0; j < 4; ++j) bfr[j] = *(const bf16x8*)(sB + (wn + j * 16 + l15) * 32 + quad * 8);
#pragma unroll
        for (int i = 0; i < MI; ++i)
#pragma unroll
            for (int j = 0; j < 4; ++j)
                acc[i][j] = __builtin_amdgcn_mfma_f32_16x16x32_bf16(af[i], bfr[j], acc[i][j], 0, 0, 0);
        __syncthreads();
    }
#pragma unroll
    for (int i = 0; i < MI; ++i) {
#pragma unroll
        for (int j = 0; j < 4; ++j) {
            const int col = col0 + wn + j * 16 + l15;
            const int row = row0 + wm + i * 16 + quad * 4;
            const float b = BIAS ? bias[col] : 0.f;
#pragma unroll
            for (int r = 0; r < 4; ++r) {
                const float v = acc[i][j][r] + b;
                if constexpr (sizeof(OUT) == 2)
                    C[(size_t)(row + r) * N + col] = (OUT)f2bf(v);
                else
                    C[(size_t)(row + r) * N + col] = (OUT)v;
            }
        }
    }
}

// ---------------------------------------------------------------------------
// relu(S) pack: bf16 round-ties-away (+0x8000>>16), b64 store to LDS
// ---------------------------------------------------------------------------
__device__ __forceinline__ void pack_store(floatx4 s, u16* dst, bool diag, int kgb, int qg) {
    float v0 = fmaxf(s[0], 0.f), v1 = fmaxf(s[1], 0.f);
    float v2 = fmaxf(s[2], 0.f), v3 = fmaxf(s[3], 0.f);
    if (diag) {                      // wave-uniform branch: only diagonal chunks
        if (kgb + 0 > qg) v0 = 0.f;
        if (kgb + 1 > qg) v1 = 0.f;
        if (kgb + 2 > qg) v2 = 0.f;
        if (kgb + 3 > qg) v3 = 0.f;
    }
    uint2v p;
    p.x = ((__builtin_bit_cast(unsigned, v0) + 0x8000u) >> 16) |
          ((__builtin_bit_cast(unsigned, v1) + 0x8000u) & 0xffff0000u);
    p.y = ((__builtin_bit_cast(unsigned, v2) + 0x8000u) >> 16) |
          ((__builtin_bit_cast(unsigned, v3) + 0x8000u) & 0xffff0000u);
    *(uint2v*)dst = p;
}

// ---------------------------------------------------------------------------
// Causal ReLU attention, tile-paired for uniform work.
// Block = (bh, pair pr): light q-tile qtl=pr (64 q), heavy qth=31-pr (64 q).
// Loop key chunks kc=0..qth; both tiles share the staged K/V chunk while the
// light tile is active (kc<=qtl). MFMA count/wave = 264 for every block.
// ---------------------------------------------------------------------------
__global__ __launch_bounds__(256) void relu_attn(const u16* __restrict__ h, const u16* __restrict__ vt,
                                                 float* __restrict__ o) {
    __shared__ u16 sK[64 * 72];    // [key][dh], stride 72
    __shared__ u16 sV[64 * 72];    // [dh][key], stride 72 (pre-scaled by 0.125)
    __shared__ u16 sP[128 * 72];   // rows 0..63 light, 64..127 heavy
    const int bid = blockIdx.x;
    const int pr = bid >> 5;            // 0 = heaviest pair, dispatched first
    const int bh = bid & 31;
    const int b = bh >> 4, hd = bh & 15;
    const int qtl = pr, qth = 31 - pr;  // 64-query tile indices
    const int tid = threadIdx.x, lane = tid & 63, wave = tid >> 6;
    const int l15 = lane & 15, quad = lane >> 4;

    // Q B-fragments (wave owns 16 queries per tile), resident all kernel
    bf16x8 qfl[2], qfh[2];
    {
        const u16* ql = h + (size_t)(b * 2048 + qtl * 64 + wave * 16 + l15) * 3072 + hd * 64;
        const u16* qh = h + (size_t)(b * 2048 + qth * 64 + wave * 16 + l15) * 3072 + hd * 64;
#pragma unroll
        for (int ks = 0; ks < 2; ++ks) {
            qfl[ks] = *(const bf16x8*)(ql + ks * 32 + quad * 8);
            qfh[ks] = *(const bf16x8*)(qh + ks * 32 + quad * 8);
        }
    }

    floatx4 accl[4] = {}, acch[4] = {};
    const u16* kbase = h + (size_t)(b * 2048) * 3072 + 1024 + hd * 64;
    const u16* vbase = vt + (size_t)bh * 64 * 2048;
    const int sr = tid >> 3;           // staging row 0..31 (+it*32)
    const int sc = (tid & 7) << 3;     // staging col 0..56
    const int qg = wave * 16 + l15;    // within-tile query (for diag mask)

    for (int kc = 0; kc <= qth; ++kc) {
        const int c0 = kc * 64;
#pragma unroll
        for (int it = 0; it < 2; ++it) {
            const int r = it * 32 + sr;
            bf16x8 kv = *(const bf16x8*)(kbase + (size_t)(c0 + r) * 3072 + sc);
            bf16x8 vv = *(const bf16x8*)(vbase + (size_t)r * 2048 + c0 + sc);
            *(bf16x8*)(sK + r * 72 + sc) = kv;
            *(bf16x8*)(sV + r * 72 + sc) = vv;
        }
        __syncthreads();
        const bool lact = (kc <= qtl);
        const floatx4 z = {0.f, 0.f, 0.f, 0.f};
        // S^T = K·Q^T; pack relu -> sP [query][key] (wave-private rows)
#pragma unroll
        for (int mt = 0; mt < 4; ++mt) {
            const bf16x8 kf0 = *(const bf16x8*)(sK + (mt * 16 + l15) * 72 + quad * 8);
            const bf16x8 kf1 = *(const bf16x8*)(sK + (mt * 16 + l15) * 72 + 32 + quad * 8);
            const int kgb = mt * 16 + quad * 4;
            floatx4 s = __builtin_amdgcn_mfma_f32_16x16x32_bf16(kf0, qfh[0], z, 0, 0, 0);
            s = __builtin_amdgcn_mfma_f32_16x16x32_bf16(kf1, qfh[1], s, 0, 0, 0);
            pack_store(s, sP + (size_t)(64 + qg) * 72 + kgb, kc == qth, kgb, qg);
            if (lact) {
                floatx4 t = __builtin_amdgcn_mfma_f32_16x16x32_bf16(kf0, qfl[0], z, 0, 0, 0);
                t = __builtin_amdgcn_mfma_f32_16x16x32_bf16(kf1, qfl[1], t, 0, 0, 0);
                pack_store(t, sP + (size_t)qg * 72 + kgb, kc == qtl, kgb, qg);
            }
        }
        // PV: O += P·V (wave reads only its own sP rows -> no extra barrier)
#pragma unroll
        for (int kb = 0; kb < 2; ++kb) {
            const bf16x8 pfh = *(const bf16x8*)(sP + (size_t)(64 + wave * 16 + l15) * 72 + kb * 32 + quad * 8);
#pragma unroll
            for (int nt = 0; nt < 4; ++nt) {
                const bf16x8 vf = *(const bf16x8*)(sV + (nt * 16 + l15) * 72 + kb * 32 + quad * 8);
                acch[nt] = __builtin_amdgcn_mfma_f32_16x16x32_bf16(pfh, vf, acch[nt], 0, 0, 0);
                if (lact) {
                    const bf16x8 pfl = *(const bf16x8*)(sP + (size_t)(wave * 16 + l15) * 72 + kb * 32 + quad * 8);
                    accl[nt] = __builtin_amdgcn_mfma_f32_16x16x32_bf16(pfl, vf, accl[nt], 0, 0, 0);
                }
            }
        }
        __syncthreads();
    }
    // epilogue: fp32 o [B,S,D], combined heads
#pragma unroll
    for (int nt = 0; nt < 4; ++nt) {
        const int col = hd * 64 + nt * 16 + l15;
        const int rl = qtl * 64 + wave * 16 + quad * 4;
        const int rh = qth * 64 + wave * 16 + quad * 4;
#pragma unroll
        for (int r = 0; r < 4; ++r) {
            o[(size_t)(b * 2048 + rl + r) * 1024 + col] = accl[nt][r];
            o[(size_t)(b * 2048 + rh + r) * 1024 + col] = acch[nt][r];
        }
    }
}

// ---------------------------------------------------------------------------
// Gated RMSNorm: one block per row of o [4096][1024] fp32 -> bf16
// ---------------------------------------------------------------------------
__global__ __launch_bounds__(256) void rms_gate(const float* __restrict__ o, const float* __restrict__ scale,
                                                const float* __restrict__ gate, u16* __restrict__ out) {
    const int row = blockIdx.x;
    const int tid = threadIdx.x;
    const floatx4* op = (const floatx4*)(o + (size_t)row * 1024);
    floatx4 v = op[tid];
    float ss = v[0] * v[0] + v[1] * v[1] + v[2] * v[2] + v[3] * v[3];
#pragma unroll
    for (int m = 32; m >= 1; m >>= 1) ss += __shfl_xor(ss, m, 64);
    __shared__ float red[4];
    if ((tid & 63) == 0) red[tid >> 6] = ss;
    __syncthreads();
    const float ms = (red[0] + red[1] + red[2] + red[3]) * (1.0f / 1024.0f);
    const float inv = rsqrtf(ms + 1e-7f);
    const int c = tid * 4;
#pragma unroll
    for (int j = 0; j < 4; ++j) {
        const float s = scale[c + j];
        const float g = gate[c + j];
        const float x = v[j];
        const float sig = 1.0f / (1.0f + __expf(-g * x));
        out[(size_t)row * 1024 + c + j] = f2bf(s * x * inv * sig);
    }
}

// ---------------------------------------------------------------------------
extern "C" void kernel_launch(void* const* d_in, const int* in_sizes, int n_in,
                              void* d_out, int out_size, void* d_ws, size_t ws_size,
                              hipStream_t stream) {
    const float* x     = (const float*)d_in[0];   // [2,2048,1024] fp32
    // d_in[1] = mem_mask: structurally causal, applied analytically
    const float* Wqkv  = (const float*)d_in[2];   // [1024,3072] fp32
    const float* Wout  = (const float*)d_in[3];   // [1024,1024] fp32
    const float* bout  = (const float*)d_in[4];   // [1024] fp32
    const float* scale = (const float*)d_in[5];   // [1024] fp32
    const float* gate  = (const float*)d_in[6];   // [1024] fp32
    float* out = (float*)d_out;                   // [2,2048,1024] fp32

    char* p = (char*)d_ws;
    u16* xb    = (u16*)p; p += (size_t)4096 * 1024 * 2;    // x in bf16
    u16* h     = (u16*)p; p += (size_t)4096 * 3072 * 2;    // qkv projection (bf16)
    u16* vt    = (u16*)p; p += (size_t)32 * 64 * 2048 * 2; // V^T [bh][dh][s], pre-scaled 0.125
    u16* WqkvT = (u16*)p; p += (size_t)3072 * 1024 * 2;
    u16* WoutT = (u16*)p; p += (size_t)1024 * 1024 * 2;
    float* oat = (float*)p; p += (size_t)4096 * 1024 * 4;  // attention out fp32
    u16* onorm = (u16*)p; p += (size_t)4096 * 1024 * 2;

    cvt_bf16<<<4096, 256, 0, stream>>>(x, xb);
    wtrans<<<dim3(96, 32), dim3(32, 8), 0, stream>>>(Wqkv, WqkvT, 1024, 3072);
    wtrans<<<dim3(32, 32), dim3(32, 8), 0, stream>>>(Wout, WoutT, 1024, 1024);
    gemm_bt<128, false, u16><<<dim3(24, 32), 256, 0, stream>>>(xb, WqkvT, h, nullptr, 4096, 3072, 1024);
    vtrans<<<dim3(64, 2, 32), dim3(32, 8), 0, stream>>>(h, vt);
    relu_attn<<<512, 256, 0, stream>>>(h, vt, oat);
    rms_gate<<<4096, 256, 0, stream>>>(oat, scale, gate, onorm);
    gemm_bt<64, true, float><<<dim3(8, 64), 256, 0, stream>>>(onorm, WoutT, out, bout, 4096, 1024, 1024);
}